// Round 1
// baseline (150.813 us; speedup 1.0000x reference)
//
#include <hip/hip_runtime.h>
#include <hip/hip_bf16.h>

// Problem constants
#define B_   4
#define C_   128
#define O_   128
#define H_   64
#define W_   64
#define HW_  (H_ * W_)
#define KW_  7
#define PAD_ 3
#define G_   8
#define CPG_ 16   // channels per group

// ---------------------------------------------------------------------------
// Kernel A: 1x1 conv projections. y[m][b][o][pix] = sum_c W_m[o][c] * x[b][c][pix]
// grid: (HW/64 tiles, B, 3 matrices), block 256.
// ---------------------------------------------------------------------------
__global__ __launch_bounds__(256) void proj3_kernel(
    const float* __restrict__ x,
    const float* __restrict__ Wq,
    const float* __restrict__ Wk,
    const float* __restrict__ Wv,
    float* __restrict__ qkv)   // [3][B][128][4096]
{
    const int tile = blockIdx.x;   // 0..63  (64 pixels each)
    const int b    = blockIdx.y;   // 0..3
    const int m    = blockIdx.z;   // 0..2
    const float* Wm = (m == 0) ? Wq : ((m == 1) ? Wk : Wv);
    float* y = qkv + ((size_t)m * B_ + b) * (size_t)C_ * HW_;
    const float* xb = x + (size_t)b * C_ * HW_;

    __shared__ float xs[C_][64];

    const int tid = threadIdx.x;
    const int p0  = tile * 64;

    // stage x slab: 128 channels x 64 pixels, float4 loads (coalesced)
    for (int idx = tid; idx < C_ * 16; idx += 256) {
        const int c  = idx >> 4;        // channel
        const int p4 = idx & 15;        // float4 within row
        const float4 v4 = *(const float4*)(xb + (size_t)c * HW_ + p0 + p4 * 4);
        *(float4*)(&xs[c][p4 * 4]) = v4;
    }
    __syncthreads();

    const int p  = tid & 63;       // pixel within tile
    const int oq = tid >> 6;       // 0..3 -> output-channel quarter

    for (int oo = 0; oo < 32; ++oo) {
        const int o = oq * 32 + oo;
        const float4* w4 = (const float4*)(Wm + (size_t)o * C_);
        float acc = 0.f;
        #pragma unroll 8
        for (int c4 = 0; c4 < C_ / 4; ++c4) {
            const float4 wv = w4[c4];
            acc += wv.x * xs[c4 * 4 + 0][p];
            acc += wv.y * xs[c4 * 4 + 1][p];
            acc += wv.z * xs[c4 * 4 + 2][p];
            acc += wv.w * xs[c4 * 4 + 3][p];
        }
        y[(size_t)o * HW_ + p0 + p] = acc;
    }
}

// ---------------------------------------------------------------------------
// Kernel B: grouped local attention. One thread per (b,g,h,w).
// grid: (HW/256, G, B), block 256.
// ---------------------------------------------------------------------------
__global__ __launch_bounds__(256) void attn_kernel(
    const float* __restrict__ qkv,
    const float* __restrict__ rel_h,   // [64][7]
    const float* __restrict__ rel_w,   // [64][7]
    float* __restrict__ out)           // [B][128][64][64]
{
    const int b   = blockIdx.z;
    const int g   = blockIdx.y;
    const int pix = blockIdx.x * 256 + threadIdx.x;   // 0..4095
    const int h   = pix >> 6;
    const int w   = pix & 63;

    const size_t plane = (size_t)B_ * C_ * HW_;
    const int c0 = g * CPG_;
    const float* qb = qkv             + ((size_t)b * C_ + c0) * HW_;
    const float* kb = qkv + plane     + ((size_t)b * C_ + c0) * HW_;
    const float* vb = qkv + 2 * plane + ((size_t)b * C_ + c0) * HW_;

    // q fragment
    float qv[CPG_];
    #pragma unroll
    for (int c = 0; c < CPG_; ++c) qv[c] = qb[(size_t)c * HW_ + pix];

    // rel score: groups 0..3 use rel_h (depends on i), 4..7 use rel_w (on j)
    const bool useH = (g < 4);
    const float* rp = useH ? (rel_h + c0 * KW_) : (rel_w + (c0 - 64) * KW_);
    float rel[KW_];
    #pragma unroll
    for (int t = 0; t < KW_; ++t) {
        float r = 0.f;
        #pragma unroll
        for (int c = 0; c < CPG_; ++c) r += qv[c] * rp[c * KW_ + t];
        rel[t] = r;
    }

    // scores (OOB window positions: k==0 from zero-pad, score = rel only)
    float s[KW_ * KW_];
    float smax = -1e30f;
    #pragma unroll
    for (int i = 0; i < KW_; ++i) {
        const int y = h + i - PAD_;
        const bool yin = ((unsigned)y < (unsigned)H_);
        #pragma unroll
        for (int j = 0; j < KW_; ++j) {
            const int x = w + j - PAD_;
            float sc = useH ? rel[i] : rel[j];
            if (yin && ((unsigned)x < (unsigned)W_)) {
                const int off = y * W_ + x;
                #pragma unroll
                for (int c = 0; c < CPG_; ++c)
                    sc += qv[c] * kb[(size_t)c * HW_ + off];
            }
            s[i * KW_ + j] = sc;
            smax = fmaxf(smax, sc);
        }
    }

    // softmax
    float denom = 0.f;
    #pragma unroll
    for (int n = 0; n < KW_ * KW_; ++n) {
        s[n] = __expf(s[n] - smax);
        denom += s[n];
    }
    const float rdenom = 1.f / denom;

    // output = attn . V  (OOB v == 0, skip)
    float acc[CPG_];
    #pragma unroll
    for (int c = 0; c < CPG_; ++c) acc[c] = 0.f;
    #pragma unroll
    for (int i = 0; i < KW_; ++i) {
        const int y = h + i - PAD_;
        if ((unsigned)y >= (unsigned)H_) continue;
        #pragma unroll
        for (int j = 0; j < KW_; ++j) {
            const int x = w + j - PAD_;
            if ((unsigned)x >= (unsigned)W_) continue;
            const float a = s[i * KW_ + j];
            const int off = y * W_ + x;
            #pragma unroll
            for (int c = 0; c < CPG_; ++c)
                acc[c] += a * vb[(size_t)c * HW_ + off];
        }
    }

    float* ob = out + ((size_t)b * C_ + c0) * HW_;
    #pragma unroll
    for (int c = 0; c < CPG_; ++c)
        ob[(size_t)c * HW_ + pix] = acc[c] * rdenom;
}

// ---------------------------------------------------------------------------
extern "C" void kernel_launch(void* const* d_in, const int* in_sizes, int n_in,
                              void* d_out, int out_size, void* d_ws, size_t ws_size,
                              hipStream_t stream) {
    const float* x     = (const float*)d_in[0];
    const float* Wq    = (const float*)d_in[1];
    const float* Wk    = (const float*)d_in[2];
    const float* Wv    = (const float*)d_in[3];
    const float* rel_h = (const float*)d_in[4];
    const float* rel_w = (const float*)d_in[5];
    float* ws  = (float*)d_ws;           // q,k,v: 3 * 4*128*4096 floats = 24 MB
    float* out = (float*)d_out;

    dim3 gA(HW_ / 64, B_, 3);
    proj3_kernel<<<gA, 256, 0, stream>>>(x, Wq, Wk, Wv, ws);

    dim3 gB(HW_ / 256, G_, B_);
    attn_kernel<<<gB, 256, 0, stream>>>(ws, rel_h, rel_w, out);
}

// Round 4
// 73.363 us; speedup vs baseline: 2.0557x; 2.0557x over previous
//
#include <hip/hip_runtime.h>
#include <hip/hip_bf16.h>

#define B_   4
#define C_   128
#define H_   64
#define W_   64
#define HW_  4096
#define KW_  7
#define PAD_ 3
#define G_   8
#define CPG_ 16

#define CPAD 136   // f16 elems per LDS row; row stride 272 B (16B-aligned)

typedef _Float16 f16x8 __attribute__((ext_vector_type(8)));
typedef float    f32x4 __attribute__((ext_vector_type(4)));

static __device__ __forceinline__ unsigned short f2h(float f) {
    _Float16 h = (_Float16)f;
    union { _Float16 h; unsigned short u; } cv; cv.h = h;
    return cv.u;
}

// ---------------------------------------------------------------------------
// Kernel A: fp16-MFMA 1x1 conv projections, output CHANNEL-PLANAR
// qkv[m][b][o][4096]  (same layout round-1 validated through graph replays)
// grid: (32 p-tiles, B, 3), block 256 (4 waves).
// ---------------------------------------------------------------------------
__global__ __launch_bounds__(256) void proj_mfma(
    const float* __restrict__ x,
    const float* __restrict__ Wq,
    const float* __restrict__ Wk,
    const float* __restrict__ Wv,
    float* __restrict__ qkv)
{
    const int ptile = blockIdx.x;
    const int b     = blockIdx.y;
    const int m     = blockIdx.z;
    const float* Wm = (m == 0) ? Wq : ((m == 1) ? Wk : Wv);
    const float* xb = x + (size_t)b * C_ * HW_;
    float* y = qkv + ((size_t)(m * B_ + b)) * C_ * HW_;
    const int p0  = ptile * 128;
    const int tid = threadIdx.x;

    __shared__ unsigned short wls[128 * CPAD];  // [o][c] f16
    __shared__ unsigned short xls[128 * CPAD];  // [p][c] f16 (transposed X)

    // stage W: 128 o x 128 c
    #pragma unroll
    for (int it = 0; it < 16; ++it) {
        const int idx = tid + it * 256;
        const int o   = idx >> 5;
        const int c4  = (idx & 31) * 4;
        const float4 w4 = *(const float4*)(Wm + (size_t)o * C_ + c4);
        ushort4 hh;
        hh.x = f2h(w4.x); hh.y = f2h(w4.y); hh.z = f2h(w4.z); hh.w = f2h(w4.w);
        *(ushort4*)(&wls[o * CPAD + c4]) = hh;
    }
    // stage X^T: 4c x 4p micro-transpose blocks
    #pragma unroll
    for (int it = 0; it < 4; ++it) {
        const int idx = tid + it * 256;
        const int cq  = (idx >> 5) * 4;
        const int pq  = (idx & 31) * 4;
        const float* xp = xb + (size_t)cq * HW_ + p0 + pq;
        const float4 r0 = *(const float4*)(xp);
        const float4 r1 = *(const float4*)(xp + HW_);
        const float4 r2 = *(const float4*)(xp + 2 * HW_);
        const float4 r3 = *(const float4*)(xp + 3 * HW_);
        ushort4 hh;
        hh.x = f2h(r0.x); hh.y = f2h(r1.x); hh.z = f2h(r2.x); hh.w = f2h(r3.x);
        *(ushort4*)(&xls[(pq + 0) * CPAD + cq]) = hh;
        hh.x = f2h(r0.y); hh.y = f2h(r1.y); hh.z = f2h(r2.y); hh.w = f2h(r3.y);
        *(ushort4*)(&xls[(pq + 1) * CPAD + cq]) = hh;
        hh.x = f2h(r0.z); hh.y = f2h(r1.z); hh.z = f2h(r2.z); hh.w = f2h(r3.z);
        *(ushort4*)(&xls[(pq + 2) * CPAD + cq]) = hh;
        hh.x = f2h(r0.w); hh.y = f2h(r1.w); hh.z = f2h(r2.w); hh.w = f2h(r3.w);
        *(ushort4*)(&xls[(pq + 3) * CPAD + cq]) = hh;
    }
    __syncthreads();

    const int wv   = tid >> 6;     // wave id: owns 32 pixels
    const int lane = tid & 63;
    const int row  = lane & 15;    // A row (p) / B col (o)
    const int kq   = lane >> 4;    // k-quad

    f32x4 acc[2][8];
    #pragma unroll
    for (int pt = 0; pt < 2; ++pt)
        #pragma unroll
        for (int ot = 0; ot < 8; ++ot)
            acc[pt][ot] = (f32x4){0.f, 0.f, 0.f, 0.f};

    #pragma unroll
    for (int ks = 0; ks < 4; ++ks) {
        const int cb = ks * 32 + kq * 8;
        const f16x8 a0 = *(const f16x8*)(&xls[(wv * 32 +      row) * CPAD + cb]);
        const f16x8 a1 = *(const f16x8*)(&xls[(wv * 32 + 16 + row) * CPAD + cb]);
        #pragma unroll
        for (int ot = 0; ot < 8; ++ot) {
            const f16x8 bfr = *(const f16x8*)(&wls[(ot * 16 + row) * CPAD + cb]);
            acc[0][ot] = __builtin_amdgcn_mfma_f32_16x16x32_f16(a0, bfr, acc[0][ot], 0, 0, 0);
            acc[1][ot] = __builtin_amdgcn_mfma_f32_16x16x32_f16(a1, bfr, acc[1][ot], 0, 0, 0);
        }
    }

    // D: lane holds D[p=(lane>>4)*4+r][o=lane&15]; 4 consecutive pixels ->
    // one float4 store per (pt,ot) into channel-planar y[o][p..p+3]
    const int pbase = p0 + wv * 32;
    #pragma unroll
    for (int pt = 0; pt < 2; ++pt) {
        const int p = pbase + pt * 16 + kq * 4;
        #pragma unroll
        for (int ot = 0; ot < 8; ++ot) {
            const int o = ot * 16 + row;
            *(float4*)(y + (size_t)o * HW_ + p) = *(const float4*)(&acc[pt][ot]);
        }
    }
}

// ---------------------------------------------------------------------------
// Kernel B: grouped local attention — VERBATIM round-1 version (replay-proven).
// grid: (HW/256, G, B), block 256.
// ---------------------------------------------------------------------------
__global__ __launch_bounds__(256) void attn_kernel(
    const float* __restrict__ qkv,
    const float* __restrict__ rel_h,   // [64][7]
    const float* __restrict__ rel_w,   // [64][7]
    float* __restrict__ out)           // [B][128][64][64]
{
    const int b   = blockIdx.z;
    const int g   = blockIdx.y;
    const int pix = blockIdx.x * 256 + threadIdx.x;   // 0..4095
    const int h   = pix >> 6;
    const int w   = pix & 63;

    const size_t plane = (size_t)B_ * C_ * HW_;
    const int c0 = g * CPG_;
    const float* qb = qkv             + ((size_t)b * C_ + c0) * HW_;
    const float* kb = qkv + plane     + ((size_t)b * C_ + c0) * HW_;
    const float* vb = qkv + 2 * plane + ((size_t)b * C_ + c0) * HW_;

    // q fragment
    float qv[CPG_];
    #pragma unroll
    for (int c = 0; c < CPG_; ++c) qv[c] = qb[(size_t)c * HW_ + pix];

    // rel score: groups 0..3 use rel_h (depends on i), 4..7 use rel_w (on j)
    const bool useH = (g < 4);
    const float* rp = useH ? (rel_h + c0 * KW_) : (rel_w + (c0 - 64) * KW_);
    float rel[KW_];
    #pragma unroll
    for (int t = 0; t < KW_; ++t) {
        float r = 0.f;
        #pragma unroll
        for (int c = 0; c < CPG_; ++c) r += qv[c] * rp[c * KW_ + t];
        rel[t] = r;
    }

    // scores (OOB window positions: k==0 from zero-pad, score = rel only)
    float s[KW_ * KW_];
    float smax = -1e30f;
    #pragma unroll
    for (int i = 0; i < KW_; ++i) {
        const int y = h + i - PAD_;
        const bool yin = ((unsigned)y < (unsigned)H_);
        #pragma unroll
        for (int j = 0; j < KW_; ++j) {
            const int x = w + j - PAD_;
            float sc = useH ? rel[i] : rel[j];
            if (yin && ((unsigned)x < (unsigned)W_)) {
                const int off = y * W_ + x;
                #pragma unroll
                for (int c = 0; c < CPG_; ++c)
                    sc += qv[c] * kb[(size_t)c * HW_ + off];
            }
            s[i * KW_ + j] = sc;
            smax = fmaxf(smax, sc);
        }
    }

    // softmax
    float denom = 0.f;
    #pragma unroll
    for (int n = 0; n < KW_ * KW_; ++n) {
        s[n] = __expf(s[n] - smax);
        denom += s[n];
    }
    const float rdenom = 1.f / denom;

    // output = attn . V  (OOB v == 0, skip)
    float acc[CPG_];
    #pragma unroll
    for (int c = 0; c < CPG_; ++c) acc[c] = 0.f;
    #pragma unroll
    for (int i = 0; i < KW_; ++i) {
        const int y = h + i - PAD_;
        if ((unsigned)y >= (unsigned)H_) continue;
        #pragma unroll
        for (int j = 0; j < KW_; ++j) {
            const int x = w + j - PAD_;
            if ((unsigned)x >= (unsigned)W_) continue;
            const float a = s[i * KW_ + j];
            const int off = y * W_ + x;
            #pragma unroll
            for (int c = 0; c < CPG_; ++c)
                acc[c] += a * vb[(size_t)c * HW_ + off];
        }
    }

    float* ob = out + ((size_t)b * C_ + c0) * HW_;
    #pragma unroll
    for (int c = 0; c < CPG_; ++c)
        ob[(size_t)c * HW_ + pix] = acc[c] * rdenom;
}

// ---------------------------------------------------------------------------
extern "C" void kernel_launch(void* const* d_in, const int* in_sizes, int n_in,
                              void* d_out, int out_size, void* d_ws, size_t ws_size,
                              hipStream_t stream) {
    const float* x     = (const float*)d_in[0];
    const float* Wq    = (const float*)d_in[1];
    const float* Wk    = (const float*)d_in[2];
    const float* Wv    = (const float*)d_in[3];
    const float* rel_h = (const float*)d_in[4];
    const float* rel_w = (const float*)d_in[5];
    float* ws  = (float*)d_ws;   // qkv channel-planar: [3][B][128][4096] fp32 = 24 MB
    float* out = (float*)d_out;

    dim3 gA(HW_ / 128, B_, 3);
    proj_mfma<<<gA, 256, 0, stream>>>(x, Wq, Wk, Wv, ws);

    dim3 gB(HW_ / 256, G_, B_);
    attn_kernel<<<gB, 256, 0, stream>>>(ws, rel_h, rel_w, out);
}

// Round 5
// 71.658 us; speedup vs baseline: 2.1046x; 1.0238x over previous
//
#include <hip/hip_runtime.h>
#include <hip/hip_bf16.h>

#define B_   4
#define C_   128
#define H_   64
#define W_   64
#define HW_  4096
#define KW_  7
#define PAD_ 3
#define G_   8
#define CPG_ 16

#define CPAD 136   // f16 elems per LDS row; row stride 272 B (16B-aligned)

typedef _Float16 f16x8 __attribute__((ext_vector_type(8)));
typedef float    f32x4 __attribute__((ext_vector_type(4)));

static __device__ __forceinline__ unsigned short f2h(float f) {
    _Float16 h = (_Float16)f;
    union { _Float16 h; unsigned short u; } cv; cv.h = h;
    return cv.u;
}

// ---------------------------------------------------------------------------
// Kernel A: fp16-MFMA 1x1 conv projections.
// Output: fp16, PIXEL-CONTIGUOUS qkv16[m][b][pix][128].
// grid: (32 p-tiles, B, 3), block 256 (4 waves).
// MFMA operand order: A = W (o free idx -> reg axis), B = X (p free idx ->
// lane&15 axis), per the round-4-validated D mapping; 4 consecutive o per
// lane pack into one ushort4 store.
// ---------------------------------------------------------------------------
__global__ __launch_bounds__(256) void proj_mfma(
    const float* __restrict__ x,
    const float* __restrict__ Wq,
    const float* __restrict__ Wk,
    const float* __restrict__ Wv,
    unsigned short* __restrict__ qkv16)
{
    const int ptile = blockIdx.x;
    const int b     = blockIdx.y;
    const int m     = blockIdx.z;
    const float* Wm = (m == 0) ? Wq : ((m == 1) ? Wk : Wv);
    const float* xb = x + (size_t)b * C_ * HW_;
    unsigned short* y = qkv16 + ((size_t)(m * B_ + b)) * HW_ * C_;
    const int p0  = ptile * 128;
    const int tid = threadIdx.x;

    __shared__ unsigned short wls[128 * CPAD];  // [o][c] f16
    __shared__ unsigned short xls[128 * CPAD];  // [p][c] f16 (transposed X)

    // stage W: 128 o x 128 c
    #pragma unroll
    for (int it = 0; it < 16; ++it) {
        const int idx = tid + it * 256;
        const int o   = idx >> 5;
        const int c4  = (idx & 31) * 4;
        const float4 w4 = *(const float4*)(Wm + (size_t)o * C_ + c4);
        ushort4 hh;
        hh.x = f2h(w4.x); hh.y = f2h(w4.y); hh.z = f2h(w4.z); hh.w = f2h(w4.w);
        *(ushort4*)(&wls[o * CPAD + c4]) = hh;
    }
    // stage X^T: 4c x 4p micro-transpose blocks
    #pragma unroll
    for (int it = 0; it < 4; ++it) {
        const int idx = tid + it * 256;
        const int cq  = (idx >> 5) * 4;
        const int pq  = (idx & 31) * 4;
        const float* xp = xb + (size_t)cq * HW_ + p0 + pq;
        const float4 r0 = *(const float4*)(xp);
        const float4 r1 = *(const float4*)(xp + HW_);
        const float4 r2 = *(const float4*)(xp + 2 * HW_);
        const float4 r3 = *(const float4*)(xp + 3 * HW_);
        ushort4 hh;
        hh.x = f2h(r0.x); hh.y = f2h(r1.x); hh.z = f2h(r2.x); hh.w = f2h(r3.x);
        *(ushort4*)(&xls[(pq + 0) * CPAD + cq]) = hh;
        hh.x = f2h(r0.y); hh.y = f2h(r1.y); hh.z = f2h(r2.y); hh.w = f2h(r3.y);
        *(ushort4*)(&xls[(pq + 1) * CPAD + cq]) = hh;
        hh.x = f2h(r0.z); hh.y = f2h(r1.z); hh.z = f2h(r2.z); hh.w = f2h(r3.z);
        *(ushort4*)(&xls[(pq + 2) * CPAD + cq]) = hh;
        hh.x = f2h(r0.w); hh.y = f2h(r1.w); hh.z = f2h(r2.w); hh.w = f2h(r3.w);
        *(ushort4*)(&xls[(pq + 3) * CPAD + cq]) = hh;
    }
    __syncthreads();

    const int wv   = tid >> 6;     // wave id: owns 32 pixels
    const int lane = tid & 63;
    const int row  = lane & 15;
    const int kq   = lane >> 4;    // k-quad

    f32x4 acc[2][8];
    #pragma unroll
    for (int pt = 0; pt < 2; ++pt)
        #pragma unroll
        for (int ot = 0; ot < 8; ++ot)
            acc[pt][ot] = (f32x4){0.f, 0.f, 0.f, 0.f};

    #pragma unroll
    for (int ks = 0; ks < 4; ++ks) {
        const int cb = ks * 32 + kq * 8;
        // B-operand: pixels (free idx -> lane&15)
        const f16x8 b0 = *(const f16x8*)(&xls[(wv * 32 +      row) * CPAD + cb]);
        const f16x8 b1 = *(const f16x8*)(&xls[(wv * 32 + 16 + row) * CPAD + cb]);
        #pragma unroll
        for (int ot = 0; ot < 8; ++ot) {
            // A-operand: output channels (free idx -> reg axis)
            const f16x8 af = *(const f16x8*)(&wls[(ot * 16 + row) * CPAD + cb]);
            acc[0][ot] = __builtin_amdgcn_mfma_f32_16x16x32_f16(af, b0, acc[0][ot], 0, 0, 0);
            acc[1][ot] = __builtin_amdgcn_mfma_f32_16x16x32_f16(af, b1, acc[1][ot], 0, 0, 0);
        }
    }

    // D: lane holds D[o = (lane>>4)*4 + reg (+16*ot)][p = lane&15 (+16*pt)]
    const int pbase = p0 + wv * 32;
    #pragma unroll
    for (int pt = 0; pt < 2; ++pt) {
        const int p = pbase + pt * 16 + row;
        unsigned short* yp = y + (size_t)p * C_;
        #pragma unroll
        for (int ot = 0; ot < 8; ++ot) {
            const int o0 = ot * 16 + kq * 4;
            ushort4 hh;
            hh.x = f2h(acc[pt][ot][0]); hh.y = f2h(acc[pt][ot][1]);
            hh.z = f2h(acc[pt][ot][2]); hh.w = f2h(acc[pt][ot][3]);
            *(ushort4*)(yp + o0) = hh;
        }
    }
}

// ---------------------------------------------------------------------------
// Kernel B: grouped local attention. No LDS; f16x8 global loads from
// pixel-contiguous fp16 qkv. One thread per (b,g,pix).
// grid: (HW/256, G, B), block 256.
// ---------------------------------------------------------------------------
__global__ __launch_bounds__(256) void attn_kernel(
    const unsigned short* __restrict__ qkv16,
    const float* __restrict__ rel_h,   // [64][7]
    const float* __restrict__ rel_w,   // [64][7]
    float* __restrict__ out)           // [B][128][64][64]
{
    const int b   = blockIdx.z;
    const int g   = blockIdx.y;
    const int pix = blockIdx.x * 256 + threadIdx.x;   // 0..4095
    const int h   = pix >> 6;
    const int w   = pix & 63;

    const size_t plane = (size_t)B_ * HW_ * C_;
    const int c0 = g * CPG_;
    const unsigned short* qb = qkv16             + (size_t)b * HW_ * C_ + c0;
    const unsigned short* kb = qkv16 + plane     + (size_t)b * HW_ * C_ + c0;
    const unsigned short* vb = qkv16 + 2 * plane + (size_t)b * HW_ * C_ + c0;

    // q fragment -> fp32
    float qv[CPG_];
    {
        const f16x8 q0 = *(const f16x8*)(qb + (size_t)pix * C_);
        const f16x8 q1 = *(const f16x8*)(qb + (size_t)pix * C_ + 8);
        #pragma unroll
        for (int c = 0; c < 8; ++c) { qv[c] = (float)q0[c]; qv[8 + c] = (float)q1[c]; }
    }

    // rel score: groups 0..3 use rel_h (index i), 4..7 use rel_w (index j)
    const bool useH = (g < 4);
    const float* rp = useH ? (rel_h + c0 * KW_) : (rel_w + (c0 - 64) * KW_);
    float rel[KW_];
    #pragma unroll
    for (int t = 0; t < KW_; ++t) {
        float r = 0.f;
        #pragma unroll
        for (int c = 0; c < CPG_; ++c) r += qv[c] * rp[c * KW_ + t];
        rel[t] = r;
    }

    // scores (OOB window positions: k==0 from zero-pad, score = rel only)
    float s[KW_ * KW_];
    float smax = -1e30f;
    #pragma unroll
    for (int i = 0; i < KW_; ++i) {
        const int y = h + i - PAD_;
        const bool yin = ((unsigned)y < (unsigned)H_);
        #pragma unroll
        for (int j = 0; j < KW_; ++j) {
            const int x = w + j - PAD_;
            float sc = useH ? rel[i] : rel[j];
            if (yin && ((unsigned)x < (unsigned)W_)) {
                const unsigned short* kp = kb + (size_t)(y * W_ + x) * C_;
                const f16x8 k0 = *(const f16x8*)(kp);
                const f16x8 k1 = *(const f16x8*)(kp + 8);
                #pragma unroll
                for (int c = 0; c < 8; ++c)
                    sc += qv[c] * (float)k0[c] + qv[8 + c] * (float)k1[c];
            }
            s[i * KW_ + j] = sc;
            smax = fmaxf(smax, sc);
        }
    }

    // softmax
    float denom = 0.f;
    #pragma unroll
    for (int n = 0; n < KW_ * KW_; ++n) {
        s[n] = __expf(s[n] - smax);
        denom += s[n];
    }
    const float rdenom = 1.f / denom;

    // output = attn . V  (OOB v == 0, skip)
    float acc[CPG_];
    #pragma unroll
    for (int c = 0; c < CPG_; ++c) acc[c] = 0.f;
    #pragma unroll
    for (int i = 0; i < KW_; ++i) {
        const int y = h + i - PAD_;
        if ((unsigned)y >= (unsigned)H_) continue;
        #pragma unroll
        for (int j = 0; j < KW_; ++j) {
            const int x = w + j - PAD_;
            if ((unsigned)x >= (unsigned)W_) continue;
            const float a = s[i * KW_ + j];
            const unsigned short* vp = vb + (size_t)(y * W_ + x) * C_;
            const f16x8 v0 = *(const f16x8*)(vp);
            const f16x8 v1 = *(const f16x8*)(vp + 8);
            #pragma unroll
            for (int c = 0; c < 8; ++c) {
                acc[c]     += a * (float)v0[c];
                acc[8 + c] += a * (float)v1[c];
            }
        }
    }

    float* ob = out + ((size_t)b * C_ + c0) * HW_;
    #pragma unroll
    for (int c = 0; c < CPG_; ++c)
        ob[(size_t)c * HW_ + pix] = acc[c] * rdenom;
}

// ---------------------------------------------------------------------------
extern "C" void kernel_launch(void* const* d_in, const int* in_sizes, int n_in,
                              void* d_out, int out_size, void* d_ws, size_t ws_size,
                              hipStream_t stream) {
    const float* x     = (const float*)d_in[0];
    const float* Wq    = (const float*)d_in[1];
    const float* Wk    = (const float*)d_in[2];
    const float* Wv    = (const float*)d_in[3];
    const float* rel_h = (const float*)d_in[4];
    const float* rel_w = (const float*)d_in[5];
    unsigned short* ws = (unsigned short*)d_ws;  // fp16 qkv [3][B][4096][128] = 12 MB
    float* out = (float*)d_out;

    dim3 gA(HW_ / 128, B_, 3);
    proj_mfma<<<gA, 256, 0, stream>>>(x, Wq, Wk, Wv, ws);

    dim3 gB(HW_ / 256, G_, B_);
    attn_kernel<<<gB, 256, 0, stream>>>(ws, rel_h, rel_w, out);
}

// Round 6
// 35.793 us; speedup vs baseline: 4.2135x; 2.0020x over previous
//
#include <hip/hip_runtime.h>
#include <hip/hip_bf16.h>

#define B_   4
#define C_   128
#define H_   64
#define W_   64
#define HW_  4096
#define KW_  7
#define PAD_ 3
#define G_   8
#define CPG_ 16

#define CPAD 136   // f16 elems per LDS row in proj; row stride 272 B

// attn LDS geometry
#define TS    16          // spatial tile
#define HALO  22          // TS + 6
#define NHP   (HALO*HALO) // 484 halo pixels
#define LP    24          // padded ushorts per pixel (48 B, 16B-aligned)

typedef _Float16 f16x8 __attribute__((ext_vector_type(8)));
typedef float    f32x4 __attribute__((ext_vector_type(4)));

static __device__ __forceinline__ unsigned short f2h(float f) {
    _Float16 h = (_Float16)f;
    union { _Float16 h; unsigned short u; } cv; cv.h = h;
    return cv.u;
}

// ---------------------------------------------------------------------------
// Kernel A: fp16-MFMA 1x1 conv projections.
// Output: fp16, GROUP-PLANAR qkv16[m][b][g][pix][16]  (pixel stride 32 B).
// grid: (32 p-tiles, B, 3), block 256 (4 waves).
// D-fragment mapping validated in round 5; only store addressing changed.
// ---------------------------------------------------------------------------
__global__ __launch_bounds__(256) void proj_mfma(
    const float* __restrict__ x,
    const float* __restrict__ Wq,
    const float* __restrict__ Wk,
    const float* __restrict__ Wv,
    unsigned short* __restrict__ qkv16)
{
    const int ptile = blockIdx.x;
    const int b     = blockIdx.y;
    const int m     = blockIdx.z;
    const float* Wm = (m == 0) ? Wq : ((m == 1) ? Wk : Wv);
    const float* xb = x + (size_t)b * C_ * HW_;
    unsigned short* y = qkv16 + ((size_t)(m * B_ + b)) * HW_ * C_;  // == ..*G*HW*CPG
    const int p0  = ptile * 128;
    const int tid = threadIdx.x;

    __shared__ unsigned short wls[128 * CPAD];  // [o][c] f16
    __shared__ unsigned short xls[128 * CPAD];  // [p][c] f16 (transposed X)

    // stage W: 128 o x 128 c
    #pragma unroll
    for (int it = 0; it < 16; ++it) {
        const int idx = tid + it * 256;
        const int o   = idx >> 5;
        const int c4  = (idx & 31) * 4;
        const float4 w4 = *(const float4*)(Wm + (size_t)o * C_ + c4);
        ushort4 hh;
        hh.x = f2h(w4.x); hh.y = f2h(w4.y); hh.z = f2h(w4.z); hh.w = f2h(w4.w);
        *(ushort4*)(&wls[o * CPAD + c4]) = hh;
    }
    // stage X^T: 4c x 4p micro-transpose blocks
    #pragma unroll
    for (int it = 0; it < 4; ++it) {
        const int idx = tid + it * 256;
        const int cq  = (idx >> 5) * 4;
        const int pq  = (idx & 31) * 4;
        const float* xp = xb + (size_t)cq * HW_ + p0 + pq;
        const float4 r0 = *(const float4*)(xp);
        const float4 r1 = *(const float4*)(xp + HW_);
        const float4 r2 = *(const float4*)(xp + 2 * HW_);
        const float4 r3 = *(const float4*)(xp + 3 * HW_);
        ushort4 hh;
        hh.x = f2h(r0.x); hh.y = f2h(r1.x); hh.z = f2h(r2.x); hh.w = f2h(r3.x);
        *(ushort4*)(&xls[(pq + 0) * CPAD + cq]) = hh;
        hh.x = f2h(r0.y); hh.y = f2h(r1.y); hh.z = f2h(r2.y); hh.w = f2h(r3.y);
        *(ushort4*)(&xls[(pq + 1) * CPAD + cq]) = hh;
        hh.x = f2h(r0.z); hh.y = f2h(r1.z); hh.z = f2h(r2.z); hh.w = f2h(r3.z);
        *(ushort4*)(&xls[(pq + 2) * CPAD + cq]) = hh;
        hh.x = f2h(r0.w); hh.y = f2h(r1.w); hh.z = f2h(r2.w); hh.w = f2h(r3.w);
        *(ushort4*)(&xls[(pq + 3) * CPAD + cq]) = hh;
    }
    __syncthreads();

    const int wv   = tid >> 6;     // wave id: owns 32 pixels
    const int lane = tid & 63;
    const int row  = lane & 15;
    const int kq   = lane >> 4;    // k-quad

    f32x4 acc[2][8];
    #pragma unroll
    for (int pt = 0; pt < 2; ++pt)
        #pragma unroll
        for (int ot = 0; ot < 8; ++ot)
            acc[pt][ot] = (f32x4){0.f, 0.f, 0.f, 0.f};

    #pragma unroll
    for (int ks = 0; ks < 4; ++ks) {
        const int cb = ks * 32 + kq * 8;
        // B-operand: pixels (free idx -> lane&15)
        const f16x8 b0 = *(const f16x8*)(&xls[(wv * 32 +      row) * CPAD + cb]);
        const f16x8 b1 = *(const f16x8*)(&xls[(wv * 32 + 16 + row) * CPAD + cb]);
        #pragma unroll
        for (int ot = 0; ot < 8; ++ot) {
            // A-operand: output channels (free idx -> reg axis)
            const f16x8 af = *(const f16x8*)(&wls[(ot * 16 + row) * CPAD + cb]);
            acc[0][ot] = __builtin_amdgcn_mfma_f32_16x16x32_f16(af, b0, acc[0][ot], 0, 0, 0);
            acc[1][ot] = __builtin_amdgcn_mfma_f32_16x16x32_f16(af, b1, acc[1][ot], 0, 0, 0);
        }
    }

    // D: lane holds D[o = ot*16 + kq*4 + reg][p = pt*16 + row (+pbase)]
    // group g == ot; within-group channel = kq*4 + reg.
    const int pbase = p0 + wv * 32;
    #pragma unroll
    for (int pt = 0; pt < 2; ++pt) {
        const int p = pbase + pt * 16 + row;
        #pragma unroll
        for (int ot = 0; ot < 8; ++ot) {
            ushort4 hh;
            hh.x = f2h(acc[pt][ot][0]); hh.y = f2h(acc[pt][ot][1]);
            hh.z = f2h(acc[pt][ot][2]); hh.w = f2h(acc[pt][ot][3]);
            *(ushort4*)(y + ((size_t)ot * HW_ + p) * CPG_ + kq * 4) = hh;
        }
    }
}

// ---------------------------------------------------------------------------
// Kernel B: grouped 7x7 local attention, fp16 K/V halo staged in LDS.
// grid: (16 tiles, G, B), block 256 = one 16x16 tile, one group.
// LDS: 2 x 484 x 24 ushorts = 45.4 KB (under 64 KB WG limit).
// OOB halo zero-filled -> no bounds branches in score/PV loops.
// ---------------------------------------------------------------------------
__global__ __launch_bounds__(256) void attn_kernel(
    const unsigned short* __restrict__ qkv16,
    const float* __restrict__ rel_h,   // [64][7]
    const float* __restrict__ rel_w,   // [64][7]
    float* __restrict__ out)           // [B][128][64][64]
{
    const int tile = blockIdx.x;
    const int g    = blockIdx.y;
    const int b    = blockIdx.z;
    const int h0   = (tile >> 2) * TS;
    const int w0   = (tile & 3) * TS;
    const int c0   = g * CPG_;

    __shared__ unsigned short kvls[2][NHP * LP];   // [k/v][pixel*24]

    const size_t gplane = (size_t)HW_ * CPG_;                 // per (b,g) plane
    const size_t mplane = (size_t)B_ * G_ * gplane;           // per matrix
    const unsigned short* qb = qkv16              + ((size_t)b * G_ + g) * gplane;
    const unsigned short* kb = qkv16 + mplane     + ((size_t)b * G_ + g) * gplane;
    const unsigned short* vb = qkv16 + 2 * mplane + ((size_t)b * G_ + g) * gplane;

    const int tid = threadIdx.x;

    // stage K and V halo: 1936 x 16B chunks, coalesced, zero-fill OOB
    #pragma unroll
    for (int it = 0; it < 8; ++it) {
        const int idx = tid + it * 256;
        if (idx < 2 * NHP * 2) {
            const int arr  = (idx >= NHP * 2) ? 1 : 0;
            const int r    = idx - arr * NHP * 2;
            const int lp   = r >> 1;
            const int half = r & 1;
            const int hy   = h0 + lp / HALO - PAD_;
            const int hx   = w0 + lp % HALO - PAD_;
            f16x8 val = (f16x8)(_Float16)0.f;
            if ((unsigned)hy < (unsigned)H_ && (unsigned)hx < (unsigned)W_) {
                const unsigned short* src = (arr ? vb : kb)
                    + (size_t)(hy * W_ + hx) * CPG_ + half * 8;
                val = *(const f16x8*)src;
            }
            *(f16x8*)(&kvls[arr][lp * LP + half * 8]) = val;
        }
    }
    __syncthreads();

    const int pw  = tid & 15;
    const int ph  = tid >> 4;
    const int pix = (h0 + ph) * W_ + (w0 + pw);

    // q fragment -> fp32
    float qv[CPG_];
    {
        const f16x8 q0 = *(const f16x8*)(qb + (size_t)pix * CPG_);
        const f16x8 q1 = *(const f16x8*)(qb + (size_t)pix * CPG_ + 8);
        #pragma unroll
        for (int c = 0; c < 8; ++c) { qv[c] = (float)q0[c]; qv[8 + c] = (float)q1[c]; }
    }

    // rel score: groups 0..3 use rel_h (index i), 4..7 use rel_w (index j)
    const bool useH = (g < 4);
    const float* rp = useH ? (rel_h + c0 * KW_) : (rel_w + (c0 - 64) * KW_);
    float rel[KW_];
    #pragma unroll
    for (int t = 0; t < KW_; ++t) {
        float r = 0.f;
        #pragma unroll
        for (int c = 0; c < CPG_; ++c) r += qv[c] * rp[c * KW_ + t];
        rel[t] = r;
    }

    // scores: all 49 positions (OOB k == 0 -> score = rel, matches zero-pad)
    float s[KW_ * KW_];
    float smax = -1e30f;
    #pragma unroll
    for (int i = 0; i < KW_; ++i) {
        #pragma unroll
        for (int j = 0; j < KW_; ++j) {
            const unsigned short* kp = &kvls[0][((ph + i) * HALO + (pw + j)) * LP];
            const f16x8 k0 = *(const f16x8*)(kp);
            const f16x8 k1 = *(const f16x8*)(kp + 8);
            float sc = useH ? rel[i] : rel[j];
            #pragma unroll
            for (int c = 0; c < 8; ++c)
                sc += qv[c] * (float)k0[c] + qv[8 + c] * (float)k1[c];
            s[i * KW_ + j] = sc;
            smax = fmaxf(smax, sc);
        }
    }

    // softmax
    float denom = 0.f;
    #pragma unroll
    for (int n = 0; n < KW_ * KW_; ++n) {
        s[n] = __expf(s[n] - smax);
        denom += s[n];
    }
    const float rdenom = 1.f / denom;

    // output = attn . V (OOB v == 0 contributes nothing)
    float acc[CPG_];
    #pragma unroll
    for (int c = 0; c < CPG_; ++c) acc[c] = 0.f;
    #pragma unroll
    for (int i = 0; i < KW_; ++i) {
        #pragma unroll
        for (int j = 0; j < KW_; ++j) {
            const float a = s[i * KW_ + j];
            const unsigned short* vp = &kvls[1][((ph + i) * HALO + (pw + j)) * LP];
            const f16x8 v0 = *(const f16x8*)(vp);
            const f16x8 v1 = *(const f16x8*)(vp + 8);
            #pragma unroll
            for (int c = 0; c < 8; ++c) {
                acc[c]     += a * (float)v0[c];
                acc[8 + c] += a * (float)v1[c];
            }
        }
    }

    float* ob = out + ((size_t)b * C_ + c0) * HW_;
    #pragma unroll
    for (int c = 0; c < CPG_; ++c)
        ob[(size_t)c * HW_ + pix] = acc[c] * rdenom;
}

// ---------------------------------------------------------------------------
extern "C" void kernel_launch(void* const* d_in, const int* in_sizes, int n_in,
                              void* d_out, int out_size, void* d_ws, size_t ws_size,
                              hipStream_t stream) {
    const float* x     = (const float*)d_in[0];
    const float* Wq    = (const float*)d_in[1];
    const float* Wk    = (const float*)d_in[2];
    const float* Wv    = (const float*)d_in[3];
    const float* rel_h = (const float*)d_in[4];
    const float* rel_w = (const float*)d_in[5];
    unsigned short* ws = (unsigned short*)d_ws;  // fp16 qkv [3][B][G][4096][16] = 12 MB
    float* out = (float*)d_out;

    dim3 gA(HW_ / 128, B_, 3);
    proj_mfma<<<gA, 256, 0, stream>>>(x, Wq, Wk, Wv, ws);

    dim3 gB(16, G_, B_);
    attn_kernel<<<gB, 256, 0, stream>>>(ws, rel_h, rel_w, out);
}